// Round 1
// baseline (919.125 us; speedup 1.0000x reference)
//
#include <hip/hip_runtime.h>

#define NN 50000      // nodes
#define NE 600000     // edges
#define HC 128        // hidden channels
#define CHN 32        // chunk size
#define NG 64         // graphs
#define LN_EPS 1e-5f

// ---------------- CSR build ----------------

__global__ void __launch_bounds__(256) k_hist(const int* __restrict__ ei, int* __restrict__ cnt) {
    int e = blockIdx.x * 256 + threadIdx.x;
    if (e >= NE) return;
    int s = ei[e], d = ei[NE + e];
    if (s != d) atomicAdd(&cnt[d], 1);
}

#define SCAN_T 1024
#define SCAN_CHUNK 49   // ceil(50000/1024)

__global__ void __launch_bounds__(SCAN_T) k_scan(const int* __restrict__ cnt, int* __restrict__ row_ptr) {
    __shared__ int sums[SCAN_T];
    int t = threadIdx.x;
    int base = t * SCAN_CHUNK;
    int s = 0;
    for (int i = 0; i < SCAN_CHUNK; ++i) {
        int idx = base + i;
        if (idx < NN) s += cnt[idx];
    }
    sums[t] = s;
    __syncthreads();
    for (int d = 1; d < SCAN_T; d <<= 1) {
        int v = (t >= d) ? sums[t - d] : 0;
        __syncthreads();
        sums[t] += v;
        __syncthreads();
    }
    int run = (t == 0) ? 0 : sums[t - 1];
    for (int i = 0; i < SCAN_CHUNK; ++i) {
        int idx = base + i;
        if (idx < NN) { row_ptr[idx] = run; run += cnt[idx]; }
    }
    if (t == SCAN_T - 1) row_ptr[NN] = sums[SCAN_T - 1];
}

__global__ void __launch_bounds__(256) k_fill(const int* __restrict__ ei, const int* __restrict__ row_ptr,
                                              int* __restrict__ fill, int* __restrict__ col) {
    int e = blockIdx.x * 256 + threadIdx.x;
    if (e >= NE) return;
    int s = ei[e], d = ei[NE + e];
    if (s != d) {
        int pos = atomicAdd(&fill[d], 1);
        col[row_ptr[d] + pos] = s;
    }
}

// ---------------- input MLP: h = LN(relu(x @ W_in + b_in)) ----------------
// one wave per node; lane owns channels (2*lane, 2*lane+1)

__global__ void __launch_bounds__(256) k_mlp(const float* __restrict__ x, const float* __restrict__ W,
                                             const float* __restrict__ b, const float* __restrict__ g,
                                             const float* __restrict__ be, float* __restrict__ h) {
    __shared__ float xs[4][HC];
    int wave = threadIdx.x >> 6, lane = threadIdx.x & 63;
    for (int node = blockIdx.x * 4 + wave; node < NN; node += gridDim.x * 4) {
        float2 xv = *(const float2*)&x[(size_t)node * HC + 2 * lane];
        xs[wave][2 * lane]     = xv.x;
        xs[wave][2 * lane + 1] = xv.y;
        float a0 = b[2 * lane], a1 = b[2 * lane + 1];
        for (int in = 0; in < HC; ++in) {
            float xb = xs[wave][in];             // wave-local LDS broadcast
            float2 wv = *(const float2*)&W[in * HC + 2 * lane];
            a0 = fmaf(xb, wv.x, a0);
            a1 = fmaf(xb, wv.y, a1);
        }
        a0 = fmaxf(a0, 0.f); a1 = fmaxf(a1, 0.f);
        float sm = a0 + a1;
        for (int m = 1; m < 64; m <<= 1) sm += __shfl_xor(sm, m, 64);
        float mu = sm * (1.f / 128.f);
        float d0 = a0 - mu, d1 = a1 - mu;
        float vv = d0 * d0 + d1 * d1;
        for (int m = 1; m < 64; m <<= 1) vv += __shfl_xor(vv, m, 64);
        float inv = rsqrtf(vv * (1.f / 128.f) + LN_EPS);
        float2 o;
        o.x = d0 * inv * g[2 * lane]     + be[2 * lane];
        o.y = d1 * inv * g[2 * lane + 1] + be[2 * lane + 1];
        *(float2*)&h[(size_t)node * HC + 2 * lane] = o;
    }
}

// ---------------- per-node CSR aggregation: agg[i] = sum_{e: dst=i, valid} h[src] ----------------

__global__ void __launch_bounds__(256) k_agg(const float* __restrict__ h, const int* __restrict__ row_ptr,
                                             const int* __restrict__ col, float* __restrict__ agg) {
    int wave = threadIdx.x >> 6, lane = threadIdx.x & 63;
    int node = blockIdx.x * 4 + wave;
    int r0 = row_ptr[node], r1 = row_ptr[node + 1];
    float ax = 0.f, ay = 0.f;
    for (int j = r0; j < r1; ++j) {
        int s = col[j];
        float2 hv = *(const float2*)&h[(size_t)s * HC + 2 * lane];
        ax += hv.x; ay += hv.y;
    }
    float2 o; o.x = ax; o.y = ay;
    *(float2*)&agg[(size_t)node * HC + 2 * lane] = o;
}

// ---------------- fused node update (gating matmul + softmax + cumsum + mix + LN) ----------------
// one wave per node. lane = 2 channels. k = lane&31 is the gate index; both 32-lane
// halves compute identical softmax/cumsum (half splits the 256-long K reduction).

__global__ void __launch_bounds__(256) k_update(float* __restrict__ h, const float* __restrict__ agg,
        const int* __restrict__ cnt, const float* __restrict__ Wtm, const float* __restrict__ btm,
        const float* __restrict__ gall, const float* __restrict__ ball, float* __restrict__ tm, int layer) {
    __shared__ float Ws[2 * HC * CHN];   // 32 KB, [256][32] row-major
    __shared__ float bs[CHN];
    __shared__ float gs[HC], bes[HC];
    __shared__ float hs[4][HC], ms[4][HC];
    int tid = threadIdx.x;
    for (int i = tid; i < 2 * HC * CHN; i += 256) Ws[i] = Wtm[i];
    if (tid < CHN) bs[tid] = btm[tid];
    if (tid < HC) { gs[tid] = gall[layer * HC + tid]; bes[tid] = ball[layer * HC + tid]; }
    __syncthreads();
    int wave = tid >> 6, lane = tid & 63;
    int k = lane & 31, half = lane >> 5;
    for (int node = blockIdx.x * 4 + wave; node < NN; node += gridDim.x * 4) {
        float2 hv = *(const float2*)&h[(size_t)node * HC + 2 * lane];
        float2 av = *(const float2*)&agg[(size_t)node * HC + 2 * lane];
        float invdeg = 1.f / (float)(cnt[node] + 1);
        float2 mv;
        mv.x = (av.x + hv.x) * invdeg;
        mv.y = (av.y + hv.y) * invdeg;
        hs[wave][2 * lane] = hv.x; hs[wave][2 * lane + 1] = hv.y;
        ms[wave][2 * lane] = mv.x; ms[wave][2 * lane + 1] = mv.y;
        // wave-local LDS only: compiler inserts the lgkmcnt wait; no block barrier needed
        const float* src = half ? ms[wave] : hs[wave];
        const float* Wr  = &Ws[half * HC * CHN];
        float z = 0.f;
        for (int c = 0; c < HC; ++c) z = fmaf(src[c], Wr[c * CHN + k], z);
        z += __shfl_xor(z, 32, 64);      // combine the two K-halves
        z += bs[k];
        // softmax over the 32 gates (width-32 ops: both halves identical)
        float mx = z;
        for (int m = 1; m < 32; m <<= 1) mx = fmaxf(mx, __shfl_xor(mx, m, 32));
        float e = expf(z - mx);
        float se = e;
        for (int m = 1; m < 32; m <<= 1) se += __shfl_xor(se, m, 32);
        float p = e / se;
        // inclusive cumsum over gate index k
        float cum = p;
        for (int d = 1; d < 32; d <<= 1) {
            float t2 = __shfl_up(cum, d, 32);
            if (k >= d) cum += t2;
        }
        float tmo = tm[(size_t)node * CHN + k];
        float raw = tmo + (1.f - tmo) * cum;
        if (half == 0) tm[(size_t)node * CHN + k] = raw;
        // sig for channels (2*lane, 2*lane+1): both in gate group lane>>1
        float sig = __shfl(raw, lane >> 1, 64);
        float v0 = hv.x * sig + mv.x * (1.f - sig);
        float v1 = hv.y * sig + mv.y * (1.f - sig);
        float sm = v0 + v1;
        for (int m = 1; m < 64; m <<= 1) sm += __shfl_xor(sm, m, 64);
        float mu = sm * (1.f / 128.f);
        float d0 = v0 - mu, d1 = v1 - mu;
        float vv = d0 * d0 + d1 * d1;
        for (int m = 1; m < 64; m <<= 1) vv += __shfl_xor(vv, m, 64);
        float inv = rsqrtf(vv * (1.f / 128.f) + LN_EPS);
        float2 o;
        o.x = d0 * inv * gs[2 * lane]     + bes[2 * lane];
        o.y = d1 * inv * gs[2 * lane + 1] + bes[2 * lane + 1];
        *(float2*)&h[(size_t)node * HC + 2 * lane] = o;
    }
}

// ---------------- global mean pool (batch is sorted) ----------------

__global__ void __launch_bounds__(128) k_pool(const float* __restrict__ h, const int* __restrict__ batch,
                                              float* __restrict__ out) {
    int g = blockIdx.x, c = threadIdx.x;
    int a = 0, bnd = NN;
    while (a < bnd) { int mid = (a + bnd) >> 1; if (batch[mid] < g) a = mid + 1; else bnd = mid; }
    int start = a;
    bnd = NN;
    while (a < bnd) { int mid = (a + bnd) >> 1; if (batch[mid] <= g) a = mid + 1; else bnd = mid; }
    int end = a;
    float acc = 0.f;
    for (int n = start; n < end; ++n) acc += h[(size_t)n * HC + c];
    int count = end - start;
    out[g * HC + c] = acc / (float)max(count, 1);
}

// ---------------- launch ----------------

extern "C" void kernel_launch(void* const* d_in, const int* in_sizes, int n_in,
                              void* d_out, int out_size, void* d_ws, size_t ws_size,
                              hipStream_t stream) {
    const float* x     = (const float*)d_in[0];
    const int*   ei    = (const int*)d_in[1];
    const int*   batch = (const int*)d_in[2];
    const float* W_in  = (const float*)d_in[3];
    const float* b_in  = (const float*)d_in[4];
    const float* g_in  = (const float*)d_in[5];
    const float* be_in = (const float*)d_in[6];
    const float* W_tm  = (const float*)d_in[7];
    const float* b_tm  = (const float*)d_in[8];
    const float* tm_g  = (const float*)d_in[9];
    const float* tm_b  = (const float*)d_in[10];
    float* out = (float*)d_out;

    char* ws = (char*)d_ws;
    int*   cnt = (int*)(ws + 0);              // NN ints
    int*   fil = (int*)(ws + 200000);         // NN ints
    int*   rp  = (int*)(ws + 400000);         // NN+1 ints
    int*   col = (int*)(ws + 600004);         // NE ints   (ends at 3,000,004)
    float* h   = (float*)(ws + 3000064);      // NN*HC floats (25.6 MB)
    float* agg = (float*)(ws + 28600064);     // NN*HC floats
    float* tm  = (float*)(ws + 54200064);     // NN*CHN floats (6.4 MB) -> end 60,600,064

    hipMemsetAsync(cnt, 0, 400000, stream);       // cnt + fil (contiguous)
    hipMemsetAsync(tm, 0, 6400000, stream);       // last_tm_signal = 0

    k_hist<<<(NE + 255) / 256, 256, 0, stream>>>(ei, cnt);
    k_scan<<<1, SCAN_T, 0, stream>>>(cnt, rp);
    k_fill<<<(NE + 255) / 256, 256, 0, stream>>>(ei, rp, fil, col);

    k_mlp<<<2048, 256, 0, stream>>>(x, W_in, b_in, g_in, be_in, h);

    for (int j = 0; j < 3; ++j) {
        k_agg<<<NN / 4, 256, 0, stream>>>(h, rp, col, agg);
        k_update<<<1024, 256, 0, stream>>>(h, agg, cnt, W_tm, b_tm, tm_g, tm_b, tm, j);
    }

    k_pool<<<NG, 128, 0, stream>>>(h, batch, out);
}

// Round 2
// 752.235 us; speedup vs baseline: 1.2219x; 1.2219x over previous
//
#include <hip/hip_runtime.h>

#define NN 50000      // nodes
#define NE 600000     // edges
#define HC 128        // hidden channels
#define CHN 32        // chunk size
#define NG 64         // graphs
#define LN_EPS 1e-5f

// ---------------- CSR build ----------------

__global__ void __launch_bounds__(256) k_hist(const int* __restrict__ ei, int* __restrict__ cnt) {
    int e = blockIdx.x * 256 + threadIdx.x;
    if (e >= NE) return;
    int s = ei[e], d = ei[NE + e];
    if (s != d) atomicAdd(&cnt[d], 1);
}

#define SCAN_T 1024
#define SCAN_CHUNK 49   // ceil(50000/1024)

__global__ void __launch_bounds__(SCAN_T) k_scan(const int* __restrict__ cnt, int* __restrict__ row_ptr) {
    __shared__ int sums[SCAN_T];
    int t = threadIdx.x;
    int base = t * SCAN_CHUNK;
    int s = 0;
    for (int i = 0; i < SCAN_CHUNK; ++i) {
        int idx = base + i;
        if (idx < NN) s += cnt[idx];
    }
    sums[t] = s;
    __syncthreads();
    for (int d = 1; d < SCAN_T; d <<= 1) {
        int v = (t >= d) ? sums[t - d] : 0;
        __syncthreads();
        sums[t] += v;
        __syncthreads();
    }
    int run = (t == 0) ? 0 : sums[t - 1];
    for (int i = 0; i < SCAN_CHUNK; ++i) {
        int idx = base + i;
        if (idx < NN) { row_ptr[idx] = run; run += cnt[idx]; }
    }
    if (t == SCAN_T - 1) row_ptr[NN] = sums[SCAN_T - 1];
}

__global__ void __launch_bounds__(256) k_fill(const int* __restrict__ ei, const int* __restrict__ row_ptr,
                                              int* __restrict__ fill, int* __restrict__ col) {
    int e = blockIdx.x * 256 + threadIdx.x;
    if (e >= NE) return;
    int s = ei[e], d = ei[NE + e];
    if (s != d) {
        int pos = atomicAdd(&fill[d], 1);
        col[row_ptr[d] + pos] = s;
    }
}

// ---------------- input MLP: h = LN(relu(x @ W_in + b_in)) ----------------
// one wave per node; lane owns channels (2*lane, 2*lane+1)

__global__ void __launch_bounds__(256) k_mlp(const float* __restrict__ x, const float* __restrict__ W,
                                             const float* __restrict__ b, const float* __restrict__ g,
                                             const float* __restrict__ be, float* __restrict__ h) {
    __shared__ float xs[4][HC];
    int wave = threadIdx.x >> 6, lane = threadIdx.x & 63;
    for (int node = blockIdx.x * 4 + wave; node < NN; node += gridDim.x * 4) {
        float2 xv = *(const float2*)&x[(size_t)node * HC + 2 * lane];
        xs[wave][2 * lane]     = xv.x;
        xs[wave][2 * lane + 1] = xv.y;
        float a0 = b[2 * lane], a1 = b[2 * lane + 1];
        for (int in = 0; in < HC; ++in) {
            float xb = xs[wave][in];             // wave-local LDS broadcast
            float2 wv = *(const float2*)&W[in * HC + 2 * lane];
            a0 = fmaf(xb, wv.x, a0);
            a1 = fmaf(xb, wv.y, a1);
        }
        a0 = fmaxf(a0, 0.f); a1 = fmaxf(a1, 0.f);
        float sm = a0 + a1;
        for (int m = 1; m < 64; m <<= 1) sm += __shfl_xor(sm, m, 64);
        float mu = sm * (1.f / 128.f);
        float d0 = a0 - mu, d1 = a1 - mu;
        float vv = d0 * d0 + d1 * d1;
        for (int m = 1; m < 64; m <<= 1) vv += __shfl_xor(vv, m, 64);
        float inv = rsqrtf(vv * (1.f / 128.f) + LN_EPS);
        float2 o;
        o.x = d0 * inv * g[2 * lane]     + be[2 * lane];
        o.y = d1 * inv * g[2 * lane + 1] + be[2 * lane + 1];
        *(float2*)&h[(size_t)node * HC + 2 * lane] = o;
    }
}

// ---------------- per-node CSR aggregation: agg[i] = sum_{e: dst=i, valid} h[src] ----------------

__global__ void __launch_bounds__(256) k_agg(const float* __restrict__ h, const int* __restrict__ row_ptr,
                                             const int* __restrict__ col, float* __restrict__ agg) {
    int wave = threadIdx.x >> 6, lane = threadIdx.x & 63;
    int node = blockIdx.x * 4 + wave;
    int r0 = row_ptr[node], r1 = row_ptr[node + 1];
    float ax = 0.f, ay = 0.f;
    for (int j = r0; j < r1; ++j) {
        int s = col[j];
        float2 hv = *(const float2*)&h[(size_t)s * HC + 2 * lane];
        ax += hv.x; ay += hv.y;
    }
    float2 o; o.x = ax; o.y = ay;
    *(float2*)&agg[(size_t)node * HC + 2 * lane] = o;
}

// ---------------- fused node update (gating matmul + softmax + cumsum + mix + LN) ----------------
// one wave per node. lane = 2 channels. k = lane&31 is the gate index; both 32-lane
// halves compute identical softmax/cumsum (half splits the 256-long K reduction).

__global__ void __launch_bounds__(256) k_update(float* __restrict__ h, const float* __restrict__ agg,
        const int* __restrict__ cnt, const float* __restrict__ Wtm, const float* __restrict__ btm,
        const float* __restrict__ gall, const float* __restrict__ ball, float* __restrict__ tm, int layer) {
    __shared__ float Ws[2 * HC * CHN];   // 32 KB, [256][32] row-major
    __shared__ float bs[CHN];
    __shared__ float gs[HC], bes[HC];
    __shared__ float hs[4][HC], ms[4][HC];
    int tid = threadIdx.x;
    for (int i = tid; i < 2 * HC * CHN; i += 256) Ws[i] = Wtm[i];
    if (tid < CHN) bs[tid] = btm[tid];
    if (tid < HC) { gs[tid] = gall[layer * HC + tid]; bes[tid] = ball[layer * HC + tid]; }
    __syncthreads();
    int wave = tid >> 6, lane = tid & 63;
    int k = lane & 31, half = lane >> 5;
    for (int node = blockIdx.x * 4 + wave; node < NN; node += gridDim.x * 4) {
        float2 hv = *(const float2*)&h[(size_t)node * HC + 2 * lane];
        float2 av = *(const float2*)&agg[(size_t)node * HC + 2 * lane];
        float invdeg = 1.f / (float)(cnt[node] + 1);
        float2 mv;
        mv.x = (av.x + hv.x) * invdeg;
        mv.y = (av.y + hv.y) * invdeg;
        hs[wave][2 * lane] = hv.x; hs[wave][2 * lane + 1] = hv.y;
        ms[wave][2 * lane] = mv.x; ms[wave][2 * lane + 1] = mv.y;
        // wave-local LDS only: compiler inserts the lgkmcnt wait; no block barrier needed
        const float* src = half ? ms[wave] : hs[wave];
        const float* Wr  = &Ws[half * HC * CHN];
        float z = 0.f;
        for (int c = 0; c < HC; ++c) z = fmaf(src[c], Wr[c * CHN + k], z);
        z += __shfl_xor(z, 32, 64);      // combine the two K-halves
        z += bs[k];
        // softmax over the 32 gates (width-32 ops: both halves identical)
        float mx = z;
        for (int m = 1; m < 32; m <<= 1) mx = fmaxf(mx, __shfl_xor(mx, m, 32));
        float e = expf(z - mx);
        float se = e;
        for (int m = 1; m < 32; m <<= 1) se += __shfl_xor(se, m, 32);
        float p = e / se;
        // inclusive cumsum over gate index k
        float cum = p;
        for (int d = 1; d < 32; d <<= 1) {
            float t2 = __shfl_up(cum, d, 32);
            if (k >= d) cum += t2;
        }
        float tmo = tm[(size_t)node * CHN + k];
        float raw = tmo + (1.f - tmo) * cum;
        if (half == 0) tm[(size_t)node * CHN + k] = raw;
        // sig for channels (2*lane, 2*lane+1): both in gate group lane>>1
        float sig = __shfl(raw, lane >> 1, 64);
        float v0 = hv.x * sig + mv.x * (1.f - sig);
        float v1 = hv.y * sig + mv.y * (1.f - sig);
        float sm = v0 + v1;
        for (int m = 1; m < 64; m <<= 1) sm += __shfl_xor(sm, m, 64);
        float mu = sm * (1.f / 128.f);
        float d0 = v0 - mu, d1 = v1 - mu;
        float vv = d0 * d0 + d1 * d1;
        for (int m = 1; m < 64; m <<= 1) vv += __shfl_xor(vv, m, 64);
        float inv = rsqrtf(vv * (1.f / 128.f) + LN_EPS);
        float2 o;
        o.x = d0 * inv * gs[2 * lane]     + bes[2 * lane];
        o.y = d1 * inv * gs[2 * lane + 1] + bes[2 * lane + 1];
        *(float2*)&h[(size_t)node * HC + 2 * lane] = o;
    }
}

// ---------------- global mean pool (batch is sorted) ----------------
// 1024 threads per graph: 8 node-slices x 128 channels, LDS tree combine.

__global__ void __launch_bounds__(1024) k_pool(const float* __restrict__ h, const int* __restrict__ batch,
                                               float* __restrict__ out) {
    __shared__ float red[8][HC];
    int g = blockIdx.x;
    int tid = threadIdx.x;
    int c = tid & (HC - 1);
    int w = tid >> 7;          // 0..7 node-slice
    int a = 0, bnd = NN;
    while (a < bnd) { int mid = (a + bnd) >> 1; if (batch[mid] < g) a = mid + 1; else bnd = mid; }
    int start = a;
    bnd = NN;
    while (a < bnd) { int mid = (a + bnd) >> 1; if (batch[mid] <= g) a = mid + 1; else bnd = mid; }
    int end = a;
    float acc = 0.f;
    for (int n = start + w; n < end; n += 8) acc += h[(size_t)n * HC + c];
    red[w][c] = acc;
    __syncthreads();
    if (w == 0) {
        float s = red[0][c] + red[1][c] + red[2][c] + red[3][c]
                + red[4][c] + red[5][c] + red[6][c] + red[7][c];
        int count = end - start;
        out[g * HC + c] = s / (float)max(count, 1);
    }
}

// ---------------- launch ----------------

extern "C" void kernel_launch(void* const* d_in, const int* in_sizes, int n_in,
                              void* d_out, int out_size, void* d_ws, size_t ws_size,
                              hipStream_t stream) {
    const float* x     = (const float*)d_in[0];
    const int*   ei    = (const int*)d_in[1];
    const int*   batch = (const int*)d_in[2];
    const float* W_in  = (const float*)d_in[3];
    const float* b_in  = (const float*)d_in[4];
    const float* g_in  = (const float*)d_in[5];
    const float* be_in = (const float*)d_in[6];
    const float* W_tm  = (const float*)d_in[7];
    const float* b_tm  = (const float*)d_in[8];
    const float* tm_g  = (const float*)d_in[9];
    const float* tm_b  = (const float*)d_in[10];
    float* out = (float*)d_out;

    char* ws = (char*)d_ws;
    int*   cnt = (int*)(ws + 0);              // NN ints
    int*   fil = (int*)(ws + 200000);         // NN ints
    int*   rp  = (int*)(ws + 400000);         // NN+1 ints
    int*   col = (int*)(ws + 600004);         // NE ints   (ends at 3,000,004)
    float* h   = (float*)(ws + 3000064);      // NN*HC floats (25.6 MB)
    float* agg = (float*)(ws + 28600064);     // NN*HC floats
    float* tm  = (float*)(ws + 54200064);     // NN*CHN floats (6.4 MB) -> end 60,600,064

    hipMemsetAsync(cnt, 0, 400000, stream);       // cnt + fil (contiguous)
    hipMemsetAsync(tm, 0, 6400000, stream);       // last_tm_signal = 0

    k_hist<<<(NE + 255) / 256, 256, 0, stream>>>(ei, cnt);
    k_scan<<<1, SCAN_T, 0, stream>>>(cnt, rp);
    k_fill<<<(NE + 255) / 256, 256, 0, stream>>>(ei, rp, fil, col);

    k_mlp<<<2048, 256, 0, stream>>>(x, W_in, b_in, g_in, be_in, h);

    for (int j = 0; j < 3; ++j) {
        k_agg<<<NN / 4, 256, 0, stream>>>(h, rp, col, agg);
        k_update<<<1024, 256, 0, stream>>>(h, agg, cnt, W_tm, b_tm, tm_g, tm_b, tm, j);
    }

    k_pool<<<NG, 1024, 0, stream>>>(h, batch, out);
}

// Round 3
// 620.922 us; speedup vs baseline: 1.4803x; 1.2115x over previous
//
#include <hip/hip_runtime.h>

#define NN 50000      // nodes
#define NE 600000     // edges
#define HC 128        // hidden channels
#define CHN 32        // chunk size
#define NG 64         // graphs
#define LN_EPS 1e-5f

// ---------------- CSR build ----------------

__global__ void __launch_bounds__(256) k_hist(const int* __restrict__ ei, int* __restrict__ cnt) {
    int e = blockIdx.x * 256 + threadIdx.x;
    if (e >= NE) return;
    int s = ei[e], d = ei[NE + e];
    if (s != d) atomicAdd(&cnt[d], 1);
}

#define SCAN_T 1024
#define SCAN_CHUNK 49   // ceil(50000/1024)

__global__ void __launch_bounds__(SCAN_T) k_scan(const int* __restrict__ cnt, int* __restrict__ row_ptr) {
    __shared__ int sums[SCAN_T];
    int t = threadIdx.x;
    int base = t * SCAN_CHUNK;
    int s = 0;
    for (int i = 0; i < SCAN_CHUNK; ++i) {
        int idx = base + i;
        if (idx < NN) s += cnt[idx];
    }
    sums[t] = s;
    __syncthreads();
    for (int d = 1; d < SCAN_T; d <<= 1) {
        int v = (t >= d) ? sums[t - d] : 0;
        __syncthreads();
        sums[t] += v;
        __syncthreads();
    }
    int run = (t == 0) ? 0 : sums[t - 1];
    for (int i = 0; i < SCAN_CHUNK; ++i) {
        int idx = base + i;
        if (idx < NN) { row_ptr[idx] = run; run += cnt[idx]; }
    }
    if (t == SCAN_T - 1) row_ptr[NN] = sums[SCAN_T - 1];
}

__global__ void __launch_bounds__(256) k_fill(const int* __restrict__ ei, const int* __restrict__ row_ptr,
                                              int* __restrict__ fill, int* __restrict__ col) {
    int e = blockIdx.x * 256 + threadIdx.x;
    if (e >= NE) return;
    int s = ei[e], d = ei[NE + e];
    if (s != d) {
        int pos = atomicAdd(&fill[d], 1);
        col[row_ptr[d] + pos] = s;
    }
}

// ---------------- input MLP: h = LN(relu(x @ W_in + b_in)) ----------------
// W staged in LDS once per block (64 KB); each wave processes 8 nodes at a
// time (16 accumulators/lane) so W LDS traffic is amortized 8x. x rows are
// wave-local LDS, read back as float4 broadcasts.

#define MLP_NB 8
#define MLP_GROUPS (NN / MLP_NB)   // 6250, exact

__global__ void __launch_bounds__(256) k_mlp(const float* __restrict__ x, const float* __restrict__ W,
                                             const float* __restrict__ b, const float* __restrict__ g,
                                             const float* __restrict__ be, float* __restrict__ h) {
    __shared__ float Ws[HC][HC];            // 64 KB
    __shared__ float xs[4][MLP_NB][HC];     // 16 KB
    int tid = threadIdx.x;
    for (int i = tid * 4; i < HC * HC; i += 256 * 4) {
        *(float4*)&((float*)Ws)[i] = *(const float4*)&W[i];
    }
    __syncthreads();
    int wave = tid >> 6, lane = tid & 63;
    float bx = b[2 * lane],  by = b[2 * lane + 1];
    float gx = g[2 * lane],  gy = g[2 * lane + 1];
    float bex = be[2 * lane], bey = be[2 * lane + 1];
    for (int grp = blockIdx.x * 4 + wave; grp < MLP_GROUPS; grp += gridDim.x * 4) {
        int base = grp * MLP_NB;
        #pragma unroll
        for (int nb = 0; nb < MLP_NB; ++nb) {
            float2 xv = *(const float2*)&x[(size_t)(base + nb) * HC + 2 * lane];
            *(float2*)&xs[wave][nb][2 * lane] = xv;
        }
        float ax[MLP_NB], ay[MLP_NB];
        #pragma unroll
        for (int nb = 0; nb < MLP_NB; ++nb) { ax[nb] = bx; ay[nb] = by; }
        // wave-local LDS: compiler inserts lgkmcnt waits; no block barrier needed
        for (int c = 0; c < HC; c += 4) {
            float2 wv0 = *(const float2*)&Ws[c + 0][2 * lane];
            float2 wv1 = *(const float2*)&Ws[c + 1][2 * lane];
            float2 wv2 = *(const float2*)&Ws[c + 2][2 * lane];
            float2 wv3 = *(const float2*)&Ws[c + 3][2 * lane];
            #pragma unroll
            for (int nb = 0; nb < MLP_NB; ++nb) {
                float4 xv = *(const float4*)&xs[wave][nb][c];
                ax[nb] = fmaf(xv.x, wv0.x, ax[nb]); ay[nb] = fmaf(xv.x, wv0.y, ay[nb]);
                ax[nb] = fmaf(xv.y, wv1.x, ax[nb]); ay[nb] = fmaf(xv.y, wv1.y, ay[nb]);
                ax[nb] = fmaf(xv.z, wv2.x, ax[nb]); ay[nb] = fmaf(xv.z, wv2.y, ay[nb]);
                ax[nb] = fmaf(xv.w, wv3.x, ax[nb]); ay[nb] = fmaf(xv.w, wv3.y, ay[nb]);
            }
        }
        #pragma unroll
        for (int nb = 0; nb < MLP_NB; ++nb) {
            float a0 = fmaxf(ax[nb], 0.f), a1 = fmaxf(ay[nb], 0.f);
            float sm = a0 + a1;
            for (int m = 1; m < 64; m <<= 1) sm += __shfl_xor(sm, m, 64);
            float mu = sm * (1.f / 128.f);
            float d0 = a0 - mu, d1 = a1 - mu;
            float vv = d0 * d0 + d1 * d1;
            for (int m = 1; m < 64; m <<= 1) vv += __shfl_xor(vv, m, 64);
            float inv = rsqrtf(vv * (1.f / 128.f) + LN_EPS);
            float2 o;
            o.x = d0 * inv * gx + bex;
            o.y = d1 * inv * gy + bey;
            *(float2*)&h[(size_t)(base + nb) * HC + 2 * lane] = o;
        }
    }
}

// ---------------- per-node CSR aggregation: agg[i] = sum_{e: dst=i, valid} h[src] ----------------

__global__ void __launch_bounds__(256) k_agg(const float* __restrict__ h, const int* __restrict__ row_ptr,
                                             const int* __restrict__ col, float* __restrict__ agg) {
    int wave = threadIdx.x >> 6, lane = threadIdx.x & 63;
    int node = blockIdx.x * 4 + wave;
    int r0 = row_ptr[node], r1 = row_ptr[node + 1];
    float ax = 0.f, ay = 0.f;
    for (int j = r0; j < r1; ++j) {
        int s = col[j];
        float2 hv = *(const float2*)&h[(size_t)s * HC + 2 * lane];
        ax += hv.x; ay += hv.y;
    }
    float2 o; o.x = ax; o.y = ay;
    *(float2*)&agg[(size_t)node * HC + 2 * lane] = o;
}

// ---------------- fused node update (gating matmul + softmax + cumsum + mix + LN) ----------------
// one wave per node. lane = 2 channels. k = lane&31 is the gate index; both 32-lane
// halves compute identical softmax/cumsum (half splits the 256-long K reduction).

__global__ void __launch_bounds__(256) k_update(float* __restrict__ h, const float* __restrict__ agg,
        const int* __restrict__ cnt, const float* __restrict__ Wtm, const float* __restrict__ btm,
        const float* __restrict__ gall, const float* __restrict__ ball, float* __restrict__ tm, int layer) {
    __shared__ float Ws[2 * HC * CHN];   // 32 KB, [256][32] row-major
    __shared__ float bs[CHN];
    __shared__ float gs[HC], bes[HC];
    __shared__ float hs[4][HC], ms[4][HC];
    int tid = threadIdx.x;
    for (int i = tid; i < 2 * HC * CHN; i += 256) Ws[i] = Wtm[i];
    if (tid < CHN) bs[tid] = btm[tid];
    if (tid < HC) { gs[tid] = gall[layer * HC + tid]; bes[tid] = ball[layer * HC + tid]; }
    __syncthreads();
    int wave = tid >> 6, lane = tid & 63;
    int k = lane & 31, half = lane >> 5;
    for (int node = blockIdx.x * 4 + wave; node < NN; node += gridDim.x * 4) {
        float2 hv = *(const float2*)&h[(size_t)node * HC + 2 * lane];
        float2 av = *(const float2*)&agg[(size_t)node * HC + 2 * lane];
        float invdeg = 1.f / (float)(cnt[node] + 1);
        float2 mv;
        mv.x = (av.x + hv.x) * invdeg;
        mv.y = (av.y + hv.y) * invdeg;
        hs[wave][2 * lane] = hv.x; hs[wave][2 * lane + 1] = hv.y;
        ms[wave][2 * lane] = mv.x; ms[wave][2 * lane + 1] = mv.y;
        // wave-local LDS only: compiler inserts the lgkmcnt wait; no block barrier needed
        const float* src = half ? ms[wave] : hs[wave];
        const float* Wr  = &Ws[half * HC * CHN];
        float z = 0.f;
        for (int c = 0; c < HC; ++c) z = fmaf(src[c], Wr[c * CHN + k], z);
        z += __shfl_xor(z, 32, 64);      // combine the two K-halves
        z += bs[k];
        // softmax over the 32 gates (width-32 ops: both halves identical)
        float mx = z;
        for (int m = 1; m < 32; m <<= 1) mx = fmaxf(mx, __shfl_xor(mx, m, 32));
        float e = expf(z - mx);
        float se = e;
        for (int m = 1; m < 32; m <<= 1) se += __shfl_xor(se, m, 32);
        float p = e / se;
        // inclusive cumsum over gate index k
        float cum = p;
        for (int d = 1; d < 32; d <<= 1) {
            float t2 = __shfl_up(cum, d, 32);
            if (k >= d) cum += t2;
        }
        float tmo = tm[(size_t)node * CHN + k];
        float raw = tmo + (1.f - tmo) * cum;
        if (half == 0) tm[(size_t)node * CHN + k] = raw;
        // sig for channels (2*lane, 2*lane+1): both in gate group lane>>1
        float sig = __shfl(raw, lane >> 1, 64);
        float v0 = hv.x * sig + mv.x * (1.f - sig);
        float v1 = hv.y * sig + mv.y * (1.f - sig);
        float sm = v0 + v1;
        for (int m = 1; m < 64; m <<= 1) sm += __shfl_xor(sm, m, 64);
        float mu = sm * (1.f / 128.f);
        float d0 = v0 - mu, d1 = v1 - mu;
        float vv = d0 * d0 + d1 * d1;
        for (int m = 1; m < 64; m <<= 1) vv += __shfl_xor(vv, m, 64);
        float inv = rsqrtf(vv * (1.f / 128.f) + LN_EPS);
        float2 o;
        o.x = d0 * inv * gs[2 * lane]     + bes[2 * lane];
        o.y = d1 * inv * gs[2 * lane + 1] + bes[2 * lane + 1];
        *(float2*)&h[(size_t)node * HC + 2 * lane] = o;
    }
}

// ---------------- global mean pool (batch is sorted) ----------------
// 1024 threads per graph: 8 node-slices x 128 channels, LDS tree combine.

__global__ void __launch_bounds__(1024) k_pool(const float* __restrict__ h, const int* __restrict__ batch,
                                               float* __restrict__ out) {
    __shared__ float red[8][HC];
    int g = blockIdx.x;
    int tid = threadIdx.x;
    int c = tid & (HC - 1);
    int w = tid >> 7;          // 0..7 node-slice
    int a = 0, bnd = NN;
    while (a < bnd) { int mid = (a + bnd) >> 1; if (batch[mid] < g) a = mid + 1; else bnd = mid; }
    int start = a;
    bnd = NN;
    while (a < bnd) { int mid = (a + bnd) >> 1; if (batch[mid] <= g) a = mid + 1; else bnd = mid; }
    int end = a;
    float acc = 0.f;
    for (int n = start + w; n < end; n += 8) acc += h[(size_t)n * HC + c];
    red[w][c] = acc;
    __syncthreads();
    if (w == 0) {
        float s = red[0][c] + red[1][c] + red[2][c] + red[3][c]
                + red[4][c] + red[5][c] + red[6][c] + red[7][c];
        int count = end - start;
        out[g * HC + c] = s / (float)max(count, 1);
    }
}

// ---------------- launch ----------------

extern "C" void kernel_launch(void* const* d_in, const int* in_sizes, int n_in,
                              void* d_out, int out_size, void* d_ws, size_t ws_size,
                              hipStream_t stream) {
    const float* x     = (const float*)d_in[0];
    const int*   ei    = (const int*)d_in[1];
    const int*   batch = (const int*)d_in[2];
    const float* W_in  = (const float*)d_in[3];
    const float* b_in  = (const float*)d_in[4];
    const float* g_in  = (const float*)d_in[5];
    const float* be_in = (const float*)d_in[6];
    const float* W_tm  = (const float*)d_in[7];
    const float* b_tm  = (const float*)d_in[8];
    const float* tm_g  = (const float*)d_in[9];
    const float* tm_b  = (const float*)d_in[10];
    float* out = (float*)d_out;

    char* ws = (char*)d_ws;
    int*   cnt = (int*)(ws + 0);              // NN ints
    int*   fil = (int*)(ws + 200000);         // NN ints
    int*   rp  = (int*)(ws + 400000);         // NN+1 ints
    int*   col = (int*)(ws + 600004);         // NE ints   (ends at 3,000,004)
    float* h   = (float*)(ws + 3000064);      // NN*HC floats (25.6 MB)
    float* agg = (float*)(ws + 28600064);     // NN*HC floats
    float* tm  = (float*)(ws + 54200064);     // NN*CHN floats (6.4 MB) -> end 60,600,064

    hipMemsetAsync(cnt, 0, 400000, stream);       // cnt + fil (contiguous)
    hipMemsetAsync(tm, 0, 6400000, stream);       // last_tm_signal = 0

    k_hist<<<(NE + 255) / 256, 256, 0, stream>>>(ei, cnt);
    k_scan<<<1, SCAN_T, 0, stream>>>(cnt, rp);
    k_fill<<<(NE + 255) / 256, 256, 0, stream>>>(ei, rp, fil, col);

    k_mlp<<<392, 256, 0, stream>>>(x, W_in, b_in, g_in, be_in, h);   // 392*4 waves ≥ enough; grid-stride over 6250 groups

    for (int j = 0; j < 3; ++j) {
        k_agg<<<NN / 4, 256, 0, stream>>>(h, rp, col, agg);
        k_update<<<1024, 256, 0, stream>>>(h, agg, cnt, W_tm, b_tm, tm_g, tm_b, tm, j);
    }

    k_pool<<<NG, 1024, 0, stream>>>(h, batch, out);
}

// Round 4
// 537.597 us; speedup vs baseline: 1.7097x; 1.1550x over previous
//
#include <hip/hip_runtime.h>

#define NN 50000      // nodes
#define NE 600000     // edges
#define HC 128        // hidden channels
#define CHN 32        // chunk size
#define NG 64         // graphs
#define LN_EPS 1e-5f

// ---------------- CSR build ----------------

__global__ void __launch_bounds__(256) k_hist(const int* __restrict__ ei, int* __restrict__ cnt) {
    int e = blockIdx.x * 256 + threadIdx.x;
    if (e >= NE) return;
    int s = ei[e], d = ei[NE + e];
    if (s != d) atomicAdd(&cnt[d], 1);
}

// ---- 3-phase device-wide exclusive scan of cnt[NN] -> row_ptr[NN+1] ----
#define SC_BLOCKS 49   // ceil(50000/1024)

__global__ void __launch_bounds__(256) k_scanA(const int* __restrict__ cnt, int* __restrict__ blocksum) {
    int b = blockIdx.x, t = threadIdx.x;
    int idx = b * 1024 + t * 4;
    int4 v = make_int4(0, 0, 0, 0);
    if (idx + 3 < NN) v = *(const int4*)&cnt[idx];
    else {
        if (idx + 0 < NN) v.x = cnt[idx + 0];
        if (idx + 1 < NN) v.y = cnt[idx + 1];
        if (idx + 2 < NN) v.z = cnt[idx + 2];
        if (idx + 3 < NN) v.w = cnt[idx + 3];
    }
    int s = v.x + v.y + v.z + v.w;
    for (int m = 1; m < 64; m <<= 1) s += __shfl_xor(s, m, 64);
    __shared__ int ws[4];
    if ((t & 63) == 0) ws[t >> 6] = s;
    __syncthreads();
    if (t == 0) blocksum[b] = ws[0] + ws[1] + ws[2] + ws[3];
}

__global__ void __launch_bounds__(64) k_scanB(const int* __restrict__ blocksum, int* __restrict__ blockoff) {
    int t = threadIdx.x;
    int v = (t < SC_BLOCKS) ? blocksum[t] : 0;
    int inc = v;
    for (int d = 1; d < 64; d <<= 1) { int u = __shfl_up(inc, d, 64); if (t >= d) inc += u; }
    if (t < SC_BLOCKS) blockoff[t + 1] = inc;
    if (t == 0) blockoff[0] = 0;
}

__global__ void __launch_bounds__(256) k_scanC(const int* __restrict__ cnt, const int* __restrict__ blockoff,
                                               int* __restrict__ row_ptr) {
    int b = blockIdx.x, t = threadIdx.x;
    int idx = b * 1024 + t * 4;
    int4 v = make_int4(0, 0, 0, 0);
    if (idx + 3 < NN) v = *(const int4*)&cnt[idx];
    else {
        if (idx + 0 < NN) v.x = cnt[idx + 0];
        if (idx + 1 < NN) v.y = cnt[idx + 1];
        if (idx + 2 < NN) v.z = cnt[idx + 2];
        if (idx + 3 < NN) v.w = cnt[idx + 3];
    }
    int s = v.x + v.y + v.z + v.w;
    int lane = t & 63, w = t >> 6;
    int inc = s;
    for (int d = 1; d < 64; d <<= 1) { int u = __shfl_up(inc, d, 64); if (lane >= d) inc += u; }
    __shared__ int wsum[4];
    if (lane == 63) wsum[w] = inc;
    __syncthreads();
    int off = blockoff[b];
    for (int i = 0; i < w; ++i) off += wsum[i];
    int excl = off + inc - s;
    if (idx + 0 < NN) row_ptr[idx + 0] = excl;
    if (idx + 1 < NN) row_ptr[idx + 1] = excl + v.x;
    if (idx + 2 < NN) row_ptr[idx + 2] = excl + v.x + v.y;
    if (idx + 3 < NN) row_ptr[idx + 3] = excl + v.x + v.y + v.z;
    if (b == 0 && t == 0) row_ptr[NN] = blockoff[SC_BLOCKS];
}

__global__ void __launch_bounds__(256) k_fill(const int* __restrict__ ei, const int* __restrict__ row_ptr,
                                              int* __restrict__ fill, int* __restrict__ col) {
    int e = blockIdx.x * 256 + threadIdx.x;
    if (e >= NE) return;
    int s = ei[e], d = ei[NE + e];
    if (s != d) {
        int pos = atomicAdd(&fill[d], 1);
        col[row_ptr[d] + pos] = s;
    }
}

// ---------------- input MLP: h = LN(relu(x @ W_in + b_in)) ----------------
// W staged in LDS once per block (64 KB); each wave processes 8 nodes at a
// time (16 accumulators/lane) so W LDS traffic is amortized 8x.

#define MLP_NB 8
#define MLP_GROUPS (NN / MLP_NB)   // 6250, exact

__global__ void __launch_bounds__(256) k_mlp(const float* __restrict__ x, const float* __restrict__ W,
                                             const float* __restrict__ b, const float* __restrict__ g,
                                             const float* __restrict__ be, float* __restrict__ h) {
    __shared__ float Ws[HC][HC];            // 64 KB
    __shared__ float xs[4][MLP_NB][HC];     // 16 KB
    int tid = threadIdx.x;
    for (int i = tid * 4; i < HC * HC; i += 256 * 4) {
        *(float4*)&((float*)Ws)[i] = *(const float4*)&W[i];
    }
    __syncthreads();
    int wave = tid >> 6, lane = tid & 63;
    float bx = b[2 * lane],  by = b[2 * lane + 1];
    float gx = g[2 * lane],  gy = g[2 * lane + 1];
    float bex = be[2 * lane], bey = be[2 * lane + 1];
    for (int grp = blockIdx.x * 4 + wave; grp < MLP_GROUPS; grp += gridDim.x * 4) {
        int base = grp * MLP_NB;
        #pragma unroll
        for (int nb = 0; nb < MLP_NB; ++nb) {
            float2 xv = *(const float2*)&x[(size_t)(base + nb) * HC + 2 * lane];
            *(float2*)&xs[wave][nb][2 * lane] = xv;
        }
        float ax[MLP_NB], ay[MLP_NB];
        #pragma unroll
        for (int nb = 0; nb < MLP_NB; ++nb) { ax[nb] = bx; ay[nb] = by; }
        // wave-local LDS: compiler inserts lgkmcnt waits; no block barrier needed
        for (int c = 0; c < HC; c += 4) {
            float2 wv0 = *(const float2*)&Ws[c + 0][2 * lane];
            float2 wv1 = *(const float2*)&Ws[c + 1][2 * lane];
            float2 wv2 = *(const float2*)&Ws[c + 2][2 * lane];
            float2 wv3 = *(const float2*)&Ws[c + 3][2 * lane];
            #pragma unroll
            for (int nb = 0; nb < MLP_NB; ++nb) {
                float4 xv = *(const float4*)&xs[wave][nb][c];
                ax[nb] = fmaf(xv.x, wv0.x, ax[nb]); ay[nb] = fmaf(xv.x, wv0.y, ay[nb]);
                ax[nb] = fmaf(xv.y, wv1.x, ax[nb]); ay[nb] = fmaf(xv.y, wv1.y, ay[nb]);
                ax[nb] = fmaf(xv.z, wv2.x, ax[nb]); ay[nb] = fmaf(xv.z, wv2.y, ay[nb]);
                ax[nb] = fmaf(xv.w, wv3.x, ax[nb]); ay[nb] = fmaf(xv.w, wv3.y, ay[nb]);
            }
        }
        #pragma unroll
        for (int nb = 0; nb < MLP_NB; ++nb) {
            float a0 = fmaxf(ax[nb], 0.f), a1 = fmaxf(ay[nb], 0.f);
            float sm = a0 + a1;
            for (int m = 1; m < 64; m <<= 1) sm += __shfl_xor(sm, m, 64);
            float mu = sm * (1.f / 128.f);
            float d0 = a0 - mu, d1 = a1 - mu;
            float vv = d0 * d0 + d1 * d1;
            for (int m = 1; m < 64; m <<= 1) vv += __shfl_xor(vv, m, 64);
            float inv = rsqrtf(vv * (1.f / 128.f) + LN_EPS);
            float2 o;
            o.x = d0 * inv * gx + bex;
            o.y = d1 * inv * gy + bey;
            *(float2*)&h[(size_t)(base + nb) * HC + 2 * lane] = o;
        }
    }
}

// ---------------- per-node CSR aggregation: agg[i] = sum_{e: dst=i, valid} h[src] ----------------

__global__ void __launch_bounds__(256) k_agg(const float* __restrict__ h, const int* __restrict__ row_ptr,
                                             const int* __restrict__ col, float* __restrict__ agg) {
    int wave = threadIdx.x >> 6, lane = threadIdx.x & 63;
    int node = blockIdx.x * 4 + wave;
    int r0 = row_ptr[node], r1 = row_ptr[node + 1];
    float ax = 0.f, ay = 0.f;
    for (int j = r0; j < r1; ++j) {
        int s = col[j];
        float2 hv = *(const float2*)&h[(size_t)s * HC + 2 * lane];
        ax += hv.x; ay += hv.y;
    }
    float2 o; o.x = ax; o.y = ay;
    *(float2*)&agg[(size_t)node * HC + 2 * lane] = o;
}

// ---------------- fused node update (gating matmul + softmax + cumsum + mix + LN) ----------------

__global__ void __launch_bounds__(256) k_update(float* __restrict__ h, const float* __restrict__ agg,
        const int* __restrict__ cnt, const float* __restrict__ Wtm, const float* __restrict__ btm,
        const float* __restrict__ gall, const float* __restrict__ ball, float* __restrict__ tm, int layer) {
    __shared__ float Ws[2 * HC * CHN];   // 32 KB, [256][32] row-major
    __shared__ float bs[CHN];
    __shared__ float gs[HC], bes[HC];
    __shared__ float hs[4][HC], ms[4][HC];
    int tid = threadIdx.x;
    for (int i = tid; i < 2 * HC * CHN; i += 256) Ws[i] = Wtm[i];
    if (tid < CHN) bs[tid] = btm[tid];
    if (tid < HC) { gs[tid] = gall[layer * HC + tid]; bes[tid] = ball[layer * HC + tid]; }
    __syncthreads();
    int wave = tid >> 6, lane = tid & 63;
    int k = lane & 31, half = lane >> 5;
    for (int node = blockIdx.x * 4 + wave; node < NN; node += gridDim.x * 4) {
        float2 hv = *(const float2*)&h[(size_t)node * HC + 2 * lane];
        float2 av = *(const float2*)&agg[(size_t)node * HC + 2 * lane];
        float invdeg = 1.f / (float)(cnt[node] + 1);
        float2 mv;
        mv.x = (av.x + hv.x) * invdeg;
        mv.y = (av.y + hv.y) * invdeg;
        hs[wave][2 * lane] = hv.x; hs[wave][2 * lane + 1] = hv.y;
        ms[wave][2 * lane] = mv.x; ms[wave][2 * lane + 1] = mv.y;
        // wave-local LDS only: compiler inserts the lgkmcnt wait; no block barrier needed
        const float* src = half ? ms[wave] : hs[wave];
        const float* Wr  = &Ws[half * HC * CHN];
        float z = 0.f;
        for (int c = 0; c < HC; ++c) z = fmaf(src[c], Wr[c * CHN + k], z);
        z += __shfl_xor(z, 32, 64);      // combine the two K-halves
        z += bs[k];
        // softmax over the 32 gates (width-32 ops: both halves identical)
        float mx = z;
        for (int m = 1; m < 32; m <<= 1) mx = fmaxf(mx, __shfl_xor(mx, m, 32));
        float e = expf(z - mx);
        float se = e;
        for (int m = 1; m < 32; m <<= 1) se += __shfl_xor(se, m, 32);
        float p = e / se;
        // inclusive cumsum over gate index k
        float cum = p;
        for (int d = 1; d < 32; d <<= 1) {
            float t2 = __shfl_up(cum, d, 32);
            if (k >= d) cum += t2;
        }
        float tmo = tm[(size_t)node * CHN + k];
        float raw = tmo + (1.f - tmo) * cum;
        if (half == 0) tm[(size_t)node * CHN + k] = raw;
        // sig for channels (2*lane, 2*lane+1): both in gate group lane>>1
        float sig = __shfl(raw, lane >> 1, 64);
        float v0 = hv.x * sig + mv.x * (1.f - sig);
        float v1 = hv.y * sig + mv.y * (1.f - sig);
        float sm = v0 + v1;
        for (int m = 1; m < 64; m <<= 1) sm += __shfl_xor(sm, m, 64);
        float mu = sm * (1.f / 128.f);
        float d0 = v0 - mu, d1 = v1 - mu;
        float vv = d0 * d0 + d1 * d1;
        for (int m = 1; m < 64; m <<= 1) vv += __shfl_xor(vv, m, 64);
        float inv = rsqrtf(vv * (1.f / 128.f) + LN_EPS);
        float2 o;
        o.x = d0 * inv * gs[2 * lane]     + bes[2 * lane];
        o.y = d1 * inv * gs[2 * lane + 1] + bes[2 * lane + 1];
        *(float2*)&h[(size_t)node * HC + 2 * lane] = o;
    }
}

// ---------------- global mean pool (batch is sorted) ----------------

__global__ void __launch_bounds__(1024) k_pool(const float* __restrict__ h, const int* __restrict__ batch,
                                               float* __restrict__ out) {
    __shared__ float red[8][HC];
    int g = blockIdx.x;
    int tid = threadIdx.x;
    int c = tid & (HC - 1);
    int w = tid >> 7;          // 0..7 node-slice
    int a = 0, bnd = NN;
    while (a < bnd) { int mid = (a + bnd) >> 1; if (batch[mid] < g) a = mid + 1; else bnd = mid; }
    int start = a;
    bnd = NN;
    while (a < bnd) { int mid = (a + bnd) >> 1; if (batch[mid] <= g) a = mid + 1; else bnd = mid; }
    int end = a;
    float acc = 0.f;
    for (int n = start + w; n < end; n += 8) acc += h[(size_t)n * HC + c];
    red[w][c] = acc;
    __syncthreads();
    if (w == 0) {
        float s = red[0][c] + red[1][c] + red[2][c] + red[3][c]
                + red[4][c] + red[5][c] + red[6][c] + red[7][c];
        int count = end - start;
        out[g * HC + c] = s / (float)max(count, 1);
    }
}

// ---------------- launch ----------------

extern "C" void kernel_launch(void* const* d_in, const int* in_sizes, int n_in,
                              void* d_out, int out_size, void* d_ws, size_t ws_size,
                              hipStream_t stream) {
    const float* x     = (const float*)d_in[0];
    const int*   ei    = (const int*)d_in[1];
    const int*   batch = (const int*)d_in[2];
    const float* W_in  = (const float*)d_in[3];
    const float* b_in  = (const float*)d_in[4];
    const float* g_in  = (const float*)d_in[5];
    const float* be_in = (const float*)d_in[6];
    const float* W_tm  = (const float*)d_in[7];
    const float* b_tm  = (const float*)d_in[8];
    const float* tm_g  = (const float*)d_in[9];
    const float* tm_b  = (const float*)d_in[10];
    float* out = (float*)d_out;

    char* ws = (char*)d_ws;
    int*   cnt = (int*)(ws + 0);              // NN ints
    int*   fil = (int*)(ws + 200000);         // NN ints
    int*   rp  = (int*)(ws + 400000);         // NN+1 ints
    int*   col = (int*)(ws + 600004);         // NE ints   (ends at 3,000,004)
    float* h   = (float*)(ws + 3000064);      // NN*HC floats (25.6 MB)
    float* agg = (float*)(ws + 28600064);     // NN*HC floats
    float* tm  = (float*)(ws + 54200064);     // NN*CHN floats (6.4 MB) -> end 60,600,064
    int*   bsum = (int*)(ws + 60600064);      // SC_BLOCKS ints
    int*   boff = (int*)(ws + 60600320);      // SC_BLOCKS+1 ints

    hipMemsetAsync(cnt, 0, 400000, stream);       // cnt + fil (contiguous)
    hipMemsetAsync(tm, 0, 6400000, stream);       // last_tm_signal = 0

    k_hist<<<(NE + 255) / 256, 256, 0, stream>>>(ei, cnt);
    k_scanA<<<SC_BLOCKS, 256, 0, stream>>>(cnt, bsum);
    k_scanB<<<1, 64, 0, stream>>>(bsum, boff);
    k_scanC<<<SC_BLOCKS, 256, 0, stream>>>(cnt, boff, rp);
    k_fill<<<(NE + 255) / 256, 256, 0, stream>>>(ei, rp, fil, col);

    k_mlp<<<392, 256, 0, stream>>>(x, W_in, b_in, g_in, be_in, h);

    for (int j = 0; j < 3; ++j) {
        k_agg<<<NN / 4, 256, 0, stream>>>(h, rp, col, agg);
        k_update<<<1024, 256, 0, stream>>>(h, agg, cnt, W_tm, b_tm, tm_g, tm_b, tm, j);
    }

    k_pool<<<NG, 1024, 0, stream>>>(h, batch, out);
}